// Round 13
// baseline (208.524 us; speedup 1.0000x reference)
//
#include <hip/hip_runtime.h>
#include <hip/hip_fp16.h>
#include <math.h>

#define N_NODES  100000
#define N_EDGES  3200000
#define N_GRAPHS 1024
#define NBUCK    782          /* buckets of 128 nodes */
#define CAP      4608         /* slots per bucket: mean 4096 + 8 sigma (16B-aligned) */
#define NPS      625          /* pair-scatter blocks */
#define ECH      5120         /* edges per block (625*5120 = 3.2M exact; 20/thread) */

__device__ inline unsigned pack2(float a, float b) {
    union { __half2 h; unsigned u; } c;
    c.h = __floats2half2_rn(a, b);
    return c.u;
}
__device__ inline float2 up2(unsigned u) {
    union { unsigned u; __half2 h; } c; c.u = u;
    return __half22float2(c.h);
}
__device__ inline void acc4(float* a, uint2 v) {
    float2 f;
    f = up2(v.x); a[0] += f.x; a[1] += f.y;
    f = up2(v.y); a[2] += f.x; a[3] += f.y;
}
__device__ inline void acc8(float* a, uint4 v) {
    float2 f;
    f = up2(v.x); a[0] += f.x; a[1] += f.y;
    f = up2(v.y); a[2] += f.x; a[3] += f.y;
    f = up2(v.z); a[4] += f.x; a[5] += f.y;
    f = up2(v.w); a[6] += f.x; a[7] += f.y;
}

// ---- K1: pair scatter, SINGLE global read (edges held in registers) ----
// pack = src | (dst&127)<<17 ; bucket = dst>>7
__global__ void k_pair_scatter(const int* __restrict__ row, const int* __restrict__ col,
                               int* __restrict__ gcursor, int* __restrict__ pairbuf) {
    __shared__ int            sbuf[ECH];    // 20.5 KB, bucket-sorted packed edges
    __shared__ unsigned short sbk[ECH];     // 10.25 KB
    __shared__ int            lhist[NBUCK]; // counts -> wbase (reused)
    __shared__ int            lcur[NBUCK];
    int t = threadIdx.x;
    const int4* col4 = (const int4*)(col + (long long)blockIdx.x * ECH);
    const int4* row4 = (const int4*)(row + (long long)blockIdx.x * ECH);
    for (int j = t; j < NBUCK; j += 256) lhist[j] = 0;
    __syncthreads();
    // pass 1: load edges ONCE into registers + histogram
    int pk[20];
    unsigned short bkr[20];
#pragma unroll
    for (int i = 0; i < 5; i++) {
        int4 c = col4[i * 256 + t];
        int4 r = row4[i * 256 + t];
        int bk;
        bk = c.x >> 7; pk[i*4+0] = r.x | ((c.x & 127) << 17); bkr[i*4+0] = (unsigned short)bk; atomicAdd(&lhist[bk], 1);
        bk = c.y >> 7; pk[i*4+1] = r.y | ((c.y & 127) << 17); bkr[i*4+1] = (unsigned short)bk; atomicAdd(&lhist[bk], 1);
        bk = c.z >> 7; pk[i*4+2] = r.z | ((c.z & 127) << 17); bkr[i*4+2] = (unsigned short)bk; atomicAdd(&lhist[bk], 1);
        bk = c.w >> 7; pk[i*4+3] = r.w | ((c.w & 127) << 17); bkr[i*4+3] = (unsigned short)bk; atomicAdd(&lhist[bk], 1);
    }
    __syncthreads();
    if (t < 64) {  // wave-0 shuffle scan -> exclusive prefix in lcur
        int carry = 0;
        for (int c0 = 0; c0 < NBUCK; c0 += 64) {
            int idx = c0 + t;
            int v = (idx < NBUCK) ? lhist[idx] : 0;
            int orig = v;
#pragma unroll
            for (int o = 1; o < 64; o <<= 1) {
                int u = __shfl_up(v, o, 64);
                if (t >= o) v += u;
            }
            if (idx < NBUCK) lcur[idx] = v - orig + carry;
            carry += __shfl(v, 63, 64);
        }
    }
    __syncthreads();
    // reserve global chunks; lhist becomes wbase
    for (int j = t; j < NBUCK; j += 256) {
        int c = lhist[j];
        int g = c ? atomicAdd(&gcursor[j], c) : 0;  // relative offset in bucket
        lhist[j] = j * CAP + g - lcur[j];
    }
    __syncthreads();
    // pass 2: place register-held edges bucket-sorted into LDS
#pragma unroll
    for (int i = 0; i < 20; i++) {
        int bk = bkr[i];
        int pos = atomicAdd(&lcur[bk], 1);
        sbuf[pos] = pk[i];
        sbk[pos] = (unsigned short)bk;
    }
    __syncthreads();
    // burst copy-out: b128 LDS reads, coalesced sequential stores per chunk
    for (int k4 = t; k4 < ECH / 4; k4 += 256) {
        int k = k4 << 2;
        int4 v = ((const int4*)sbuf)[k4];
        ushort4 bb = ((const ushort4*)sbk)[k4];
        int p0 = lhist[bb.x] + k;
        int p1 = lhist[bb.y] + k + 1;
        int p2 = lhist[bb.z] + k + 2;
        int p3 = lhist[bb.w] + k + 3;
        if (p0 < (bb.x + 1) * CAP) pairbuf[p0] = v.x;  // overflow guards (never expected)
        if (p1 < (bb.y + 1) * CAP) pairbuf[p1] = v.y;
        if (p2 < (bb.z + 1) * CAP) pairbuf[p2] = v.z;
        if (p3 < (bb.w + 1) * CAP) pairbuf[p3] = v.w;
    }
}

// ---- K2: per-bucket CSR finalize IN PLACE + dinv + bufA16 = fp16(x*dinv) [4 halfs] ----
__global__ void k_finalize(int* __restrict__ pairbuf, const int* __restrict__ gcursor,
                           int2* __restrict__ rowse, float* __restrict__ dinv,
                           const float* __restrict__ x, __half* __restrict__ bufA16) {
    __shared__ int slice[CAP];   // 18.4 KB
    __shared__ int lcnt[128];
    __shared__ int ls[128];
    __shared__ int cur[128];
    int t = threadIdx.x, b = blockIdx.x;
    int base = b * CAP;
    int cnt_b = gcursor[b];                 // relative fill
    if (cnt_b > CAP) cnt_b = CAP;
    int cnt4 = cnt_b >> 2;
    if (t < 128) lcnt[t] = 0;
    {   // int4 staging + scalar tail
        const int4* pb4 = (const int4*)(pairbuf + base);
        for (int k4 = t; k4 < cnt4; k4 += 256) ((int4*)slice)[k4] = pb4[k4];
        int k = (cnt4 << 2) + t;
        if (k < cnt_b) slice[k] = pairbuf[base + k];
    }
    __syncthreads();
    for (int k4 = t; k4 < cnt4; k4 += 256) {
        int4 v = ((const int4*)slice)[k4];
        atomicAdd(&lcnt[(v.x >> 17) & 127], 1);
        atomicAdd(&lcnt[(v.y >> 17) & 127], 1);
        atomicAdd(&lcnt[(v.z >> 17) & 127], 1);
        atomicAdd(&lcnt[(v.w >> 17) & 127], 1);
    }
    {
        int k = (cnt4 << 2) + t;
        if (k < cnt_b) atomicAdd(&lcnt[(slice[k] >> 17) & 127], 1);
    }
    __syncthreads();
    int myc = (t < 128) ? lcnt[t] : 0;
    if (t < 128) ls[t] = myc;
    __syncthreads();
    for (int o = 1; o < 128; o <<= 1) {
        int v = (t < 128 && t >= o) ? ls[t - o] : 0;
        __syncthreads();
        if (t < 128) ls[t] += v;
        __syncthreads();
    }
    int node = (b << 7) + t;
    if (t < 128) {
        int st = base + ls[t] - myc;
        cur[t] = st;
        if (node < N_NODES) {
            rowse[node] = make_int2(st, st + myc);
            float d = rsqrtf((float)(myc + 1));  // +1 self loop
            dinv[node] = d;
            // bufA16[node] = fp16(x[node] * d), 4 halfs (pad 0)
            float x0 = x[node * 3 + 0], x1 = x[node * 3 + 1], x2 = x[node * 3 + 2];
            uint2 u = { pack2(x0 * d, x1 * d), pack2(x2 * d, 0.f) };
            ((uint2*)(bufA16 + (long long)node * 4))[0] = u;
        }
    }
    __syncthreads();
    // in-place sorted write-back (slice fully staged in LDS -> safe)
    for (int k4 = t; k4 < cnt4; k4 += 256) {
        int4 v = ((const int4*)slice)[k4];
        int pos;
        pos = atomicAdd(&cur[(v.x >> 17) & 127], 1); pairbuf[pos] = v.x & 0x1FFFF;
        pos = atomicAdd(&cur[(v.y >> 17) & 127], 1); pairbuf[pos] = v.y & 0x1FFFF;
        pos = atomicAdd(&cur[(v.z >> 17) & 127], 1); pairbuf[pos] = v.z & 0x1FFFF;
        pos = atomicAdd(&cur[(v.w >> 17) & 127], 1); pairbuf[pos] = v.w & 0x1FFFF;
    }
    {
        int k = (cnt4 << 2) + t;
        if (k < cnt_b) {
            int p = slice[k];
            int pos = atomicAdd(&cur[(p >> 17) & 127], 1);
            pairbuf[pos] = p & 0x1FFFF;
        }
    }
}

// ---- K3: gather layer1 (4-wide x rows) + full fused layer1+layer2 transform ----
// 1 lane/node. p = sum(x*dinv); h = relu(d*p@W1 + b1); out16 = fp16((h@W2)*d)
__global__ void k_gather1(const uint2* __restrict__ src16, const int* __restrict__ csr,
                          const int2* __restrict__ rowse, const float* __restrict__ dinv,
                          const float* __restrict__ W1, const float* __restrict__ b1,
                          const float* __restrict__ W2, __half* __restrict__ out16) {
    __shared__ float sW1[48];
    __shared__ float sb1[16];
    __shared__ float sW2[256];
    int t = threadIdx.x;
    sW2[t] = W2[t];
    if (t < 48) sW1[t] = W1[t];
    if (t < 16) sb1[t] = b1[t];
    __syncthreads();
    int node = blockIdx.x * 256 + t;
    if (node >= N_NODES) return;
    int2 se = rowse[node];
    int s = se.x, e = se.y;
    float p[4];
    {
        uint2 u = src16[node];  // self loop (pre-scaled)
        float2 f;
        f = up2(u.x); p[0] = f.x; p[1] = f.y;
        f = up2(u.y); p[2] = f.x; p[3] = f.y;
    }
    int j = s;
    for (; j < e && (j & 3); j++) acc4(p, src16[csr[j]]);  // align
    for (; j + 8 <= e; j += 8) {
        int4 ia = *(const int4*)(csr + j);
        int4 ib = *(const int4*)(csr + j + 4);
        uint2 v0 = src16[ia.x], v1 = src16[ia.y], v2 = src16[ia.z], v3 = src16[ia.w];
        uint2 v4 = src16[ib.x], v5 = src16[ib.y], v6 = src16[ib.z], v7 = src16[ib.w];
        acc4(p, v0); acc4(p, v1); acc4(p, v2); acc4(p, v3);
        acc4(p, v4); acc4(p, v5); acc4(p, v6); acc4(p, v7);
    }
    for (; j < e; j++) acc4(p, src16[csr[j]]);
    float d = dinv[node];
    float q0 = p[0] * d, q1 = p[1] * d, q2 = p[2] * d;
    float h[16];
#pragma unroll
    for (int k = 0; k < 16; k++) {
        float v = q0 * sW1[k] + q1 * sW1[16 + k] + q2 * sW1[32 + k] + sb1[k];
        h[k] = v > 0.f ? v : 0.f;
    }
    float v[16];
#pragma unroll
    for (int jj = 0; jj < 16; jj++) {
        float a = 0.f;
#pragma unroll
        for (int k = 0; k < 16; k++) a += h[k] * sW2[k * 16 + jj];
        v[jj] = a * d;  // prescale for layer 2
    }
    uint4 u0 = { pack2(v[0], v[1]), pack2(v[2], v[3]), pack2(v[4], v[5]), pack2(v[6], v[7]) };
    uint4 u1 = { pack2(v[8], v[9]), pack2(v[10], v[11]), pack2(v[12], v[13]), pack2(v[14], v[15]) };
    uint4* op = (uint4*)(out16 + (long long)node * 16);
    op[0] = u0; op[1] = u1;
}

// ---- K4: gather layer2 + fused pool. 256 thr, 128 nodes, 2 lanes/node, uint4 ----
__global__ void k_gather2(const uint4* __restrict__ src16, const int* __restrict__ csr,
                          const int2* __restrict__ rowse, const float* __restrict__ dinv,
                          const int* __restrict__ batch, float* __restrict__ pooled) {
    __shared__ float pl[8][16];
    __shared__ int ginfo[2];   // gmin, gmax
    int t = threadIdx.x;
    int node0 = blockIdx.x * 128;
    if (t < 128) pl[t >> 4][t & 15] = 0.f;
    if (t == 0) {
        int last = node0 + 127; if (last >= N_NODES) last = N_NODES - 1;
        ginfo[0] = batch[node0];
        ginfo[1] = batch[last];
    }
    __syncthreads();
    int node = node0 + (t >> 1);
    int h = t & 1;
    bool act = node < N_NODES;
    if (act) {
        int2 se = rowse[node];
        int s = se.x, e = se.y;
        float o[8] = {0, 0, 0, 0, 0, 0, 0, 0};
        acc8(o, src16[node * 2 + h]);  // self loop (pre-scaled)
        int j = s;
        for (; j < e && (j & 3); j++) acc8(o, src16[csr[j] * 2 + h]);  // align
        for (; j + 8 <= e; j += 8) {
            int4 ia = *(const int4*)(csr + j);
            int4 ib = *(const int4*)(csr + j + 4);
            uint4 v0 = src16[ia.x * 2 + h], v1 = src16[ia.y * 2 + h];
            uint4 v2 = src16[ia.z * 2 + h], v3 = src16[ia.w * 2 + h];
            uint4 v4 = src16[ib.x * 2 + h], v5 = src16[ib.y * 2 + h];
            uint4 v6 = src16[ib.z * 2 + h], v7 = src16[ib.w * 2 + h];
            acc8(o, v0); acc8(o, v1); acc8(o, v2); acc8(o, v3);
            acc8(o, v4); acc8(o, v5); acc8(o, v6); acc8(o, v7);
        }
        for (; j < e; j++) acc8(o, src16[csr[j] * 2 + h]);
        float d = dinv[node];
#pragma unroll
        for (int k = 0; k < 8; k++) o[k] *= d;
        int slot = batch[node] - ginfo[0];
        if (slot < 8) {
#pragma unroll
            for (int k = 0; k < 8; k++) atomicAdd(&pl[slot][h * 8 + k], o[k]);
        } else {  // pathological span (never expected)
#pragma unroll
            for (int k = 0; k < 8; k++) atomicAdd(&pooled[batch[node] * 16 + h * 8 + k], o[k]);
        }
    }
    __syncthreads();
    if (t < 128) {
        int s = t >> 4, f = t & 15;
        int span = ginfo[1] - ginfo[0];
        if (s <= span && s < 8)
            atomicAdd(&pooled[(ginfo[0] + s) * 16 + f], pl[s][f]);
    }
}

// ---- K5: head: logits = (pooled + cnt*b2) @ Wl + bl; log_softmax ----
__global__ void k_head(const float* __restrict__ pooled, const int* __restrict__ batch,
                       const float* __restrict__ b2, const float* __restrict__ Wl,
                       const float* __restrict__ bl, float* __restrict__ out) {
    int g = blockIdx.x;
    int t = threadIdx.x;  // 64 threads = 1 wave
    __shared__ int range[2];
    __shared__ float pld[16];
    __shared__ float logits[7];
    if (t < 2) {
        int target = g + t;
        int lo = 0, hi = N_NODES;
        while (lo < hi) {
            int mid = (lo + hi) >> 1;
            if (batch[mid] < target) lo = mid + 1; else hi = mid;
        }
        range[t] = lo;
    }
    __syncthreads();
    float cnt = (float)(range[1] - range[0]);
    if (t < 16) pld[t] = pooled[g * 16 + t] + cnt * b2[t];
    __syncthreads();
    if (t < 7) {
        float a = bl[t];
#pragma unroll
        for (int k = 0; k < 16; k++) a += pld[k] * Wl[k * 7 + t];
        logits[t] = a;
    }
    __syncthreads();
    if (t == 0) {
        float m = logits[0];
#pragma unroll
        for (int c = 1; c < 7; c++) m = fmaxf(m, logits[c]);
        float sum = 0.f;
#pragma unroll
        for (int c = 0; c < 7; c++) sum += expf(logits[c] - m);
        float lse = logf(sum) + m;
#pragma unroll
        for (int c = 0; c < 7; c++) out[g * 7 + c] = logits[c] - lse;
    }
}

extern "C" void kernel_launch(void* const* d_in, const int* in_sizes, int n_in,
                              void* d_out, int out_size, void* d_ws, size_t ws_size,
                              hipStream_t stream) {
    const float* x     = (const float*)d_in[0];
    const int*   ei    = (const int*)d_in[1];
    const int*   batch = (const int*)d_in[2];
    const float* W1    = (const float*)d_in[3];
    const float* b1    = (const float*)d_in[4];
    const float* W2    = (const float*)d_in[5];
    const float* b2    = (const float*)d_in[6];
    const float* Wl    = (const float*)d_in[7];
    const float* bl    = (const float*)d_in[8];
    float* out = (float*)d_out;

    const int* row = ei;            // sources
    const int* col = ei + N_EDGES;  // targets

    // ws layout (4-byte words). pairbuf becomes csr in place (k_finalize).
    int*    gcursor = (int*)d_ws;                      // @0        782 (pad 800)
    float*  pooled  = (float*)d_ws + 800;              // @800      16384 (1024*16)
    float*  dinv    = (float*)d_ws + 17200;            // @17200    100000
    int2*   rowse   = (int2*)((int*)d_ws + 117200);    // @117200   200000 words
    int*    pairbuf = (int*)d_ws + 317200;             // @317200   782*4608 = 3603456 (-> csr)
    __half* bufA16  = (__half*)((int*)d_ws + 3920656); // @3920656  200000 words (16B-aligned)
    __half* bufB16  = (__half*)((int*)d_ws + 4120656); // @4120656  800000 words (16B-aligned)

    const int BT = 256;

    hipMemsetAsync(gcursor, 0, 17184 * sizeof(int), stream);  // gcursor + pooled
    k_pair_scatter<<<NPS, BT, 0, stream>>>(row, col, gcursor, pairbuf);
    k_finalize<<<NBUCK, BT, 0, stream>>>(pairbuf, gcursor, rowse, dinv, x, bufA16);
    k_gather1<<<(N_NODES + 255) / 256, BT, 0, stream>>>((const uint2*)bufA16, pairbuf, rowse,
                                                        dinv, W1, b1, W2, bufB16);
    k_gather2<<<(N_NODES + 127) / 128, BT, 0, stream>>>((const uint4*)bufB16, pairbuf, rowse,
                                                        dinv, batch, pooled);
    k_head<<<N_GRAPHS, 64, 0, stream>>>(pooled, batch, b2, Wl, bl, out);
}

// Round 14
// 204.234 us; speedup vs baseline: 1.0210x; 1.0210x over previous
//
#include <hip/hip_runtime.h>
#include <hip/hip_fp16.h>
#include <math.h>

#define N_NODES  100000
#define N_EDGES  3200000
#define N_GRAPHS 1024
#define NBUCK    782          /* buckets of 128 nodes */
#define CAP      4608         /* slots per bucket: mean 4096 + 8 sigma (16B-aligned) */
#define NPS      500          /* pair-scatter blocks */
#define ECH      6400         /* edges per block (500*6400 = 3.2M; 16B-aligned base) */

__device__ inline unsigned pack2(float a, float b) {
    union { __half2 h; unsigned u; } c;
    c.h = __floats2half2_rn(a, b);
    return c.u;
}
__device__ inline float2 up2(unsigned u) {
    union { unsigned u; __half2 h; } c; c.u = u;
    return __half22float2(c.h);
}
__device__ inline void acc4(float* a, uint2 v) {
    float2 f;
    f = up2(v.x); a[0] += f.x; a[1] += f.y;
    f = up2(v.y); a[2] += f.x; a[3] += f.y;
}
__device__ inline void acc8(float* a, uint4 v) {
    float2 f;
    f = up2(v.x); a[0] += f.x; a[1] += f.y;
    f = up2(v.y); a[2] += f.x; a[3] += f.y;
    f = up2(v.z); a[4] += f.x; a[5] += f.y;
    f = up2(v.w); a[6] += f.x; a[7] += f.y;
}

// ---- K1: pair scatter, int4 streams, in-LDS bucket sort + burst copy-out ----
// (R12's proven version: two passes over col; 2nd pass hits LLC, costs no HBM)
// pack = src | (dst&127)<<17 ; bucket = dst>>7
__global__ void k_pair_scatter(const int* __restrict__ row, const int* __restrict__ col,
                               int* __restrict__ gcursor, int* __restrict__ pairbuf) {
    __shared__ int            sbuf[ECH];    // 25.6 KB
    __shared__ unsigned short sbk[ECH];     // 12.8 KB
    __shared__ int            lhist[NBUCK]; // counts -> wbase (reused)
    __shared__ int            lcur[NBUCK];
    int t = threadIdx.x;
    int e0 = blockIdx.x * ECH;
    const int4* col4 = (const int4*)(col + e0);
    const int4* row4 = (const int4*)(row + e0);
    for (int j = t; j < NBUCK; j += 256) lhist[j] = 0;
    __syncthreads();
    // pass 1: histogram, 4 edges/lane/iter
    for (int k = t; k < ECH / 4; k += 256) {
        int4 c = col4[k];
        atomicAdd(&lhist[c.x >> 7], 1);
        atomicAdd(&lhist[c.y >> 7], 1);
        atomicAdd(&lhist[c.z >> 7], 1);
        atomicAdd(&lhist[c.w >> 7], 1);
    }
    __syncthreads();
    if (t < 64) {  // wave-0 shuffle scan -> exclusive prefix in lcur
        int carry = 0;
        for (int c0 = 0; c0 < NBUCK; c0 += 64) {
            int idx = c0 + t;
            int v = (idx < NBUCK) ? lhist[idx] : 0;
            int orig = v;
#pragma unroll
            for (int o = 1; o < 64; o <<= 1) {
                int u = __shfl_up(v, o, 64);
                if (t >= o) v += u;
            }
            if (idx < NBUCK) lcur[idx] = v - orig + carry;
            carry += __shfl(v, 63, 64);
        }
    }
    __syncthreads();
    // reserve global chunks; lhist becomes wbase
    for (int j = t; j < NBUCK; j += 256) {
        int c = lhist[j];
        int g = c ? atomicAdd(&gcursor[j], c) : 0;  // relative offset in bucket
        lhist[j] = j * CAP + g - lcur[j];
    }
    __syncthreads();
    // pass 2: place edges bucket-sorted in LDS, 4 edges/lane/iter
    for (int k = t; k < ECH / 4; k += 256) {
        int4 c = col4[k];
        int4 r = row4[k];
        int bk, pos;
        bk = c.x >> 7; pos = atomicAdd(&lcur[bk], 1);
        sbuf[pos] = r.x | ((c.x & 127) << 17); sbk[pos] = (unsigned short)bk;
        bk = c.y >> 7; pos = atomicAdd(&lcur[bk], 1);
        sbuf[pos] = r.y | ((c.y & 127) << 17); sbk[pos] = (unsigned short)bk;
        bk = c.z >> 7; pos = atomicAdd(&lcur[bk], 1);
        sbuf[pos] = r.z | ((c.z & 127) << 17); sbk[pos] = (unsigned short)bk;
        bk = c.w >> 7; pos = atomicAdd(&lcur[bk], 1);
        sbuf[pos] = r.w | ((c.w & 127) << 17); sbk[pos] = (unsigned short)bk;
    }
    __syncthreads();
    // burst copy-out: b128 LDS reads, coalesced sequential stores per chunk
    for (int k4 = t; k4 < ECH / 4; k4 += 256) {
        int k = k4 << 2;
        int4 v = ((const int4*)sbuf)[k4];
        ushort4 bb = ((const ushort4*)sbk)[k4];
        int p0 = lhist[bb.x] + k;
        int p1 = lhist[bb.y] + k + 1;
        int p2 = lhist[bb.z] + k + 2;
        int p3 = lhist[bb.w] + k + 3;
        if (p0 < (bb.x + 1) * CAP) pairbuf[p0] = v.x;  // overflow guards (never expected)
        if (p1 < (bb.y + 1) * CAP) pairbuf[p1] = v.y;
        if (p2 < (bb.z + 1) * CAP) pairbuf[p2] = v.z;
        if (p3 < (bb.w + 1) * CAP) pairbuf[p3] = v.w;
    }
}

// ---- K2: per-bucket CSR finalize IN PLACE + dinv + bufA16 = fp16(x*dinv) [4 halfs] ----
__global__ void k_finalize(int* __restrict__ pairbuf, const int* __restrict__ gcursor,
                           int2* __restrict__ rowse, float* __restrict__ dinv,
                           const float* __restrict__ x, __half* __restrict__ bufA16) {
    __shared__ int slice[CAP];   // 18.4 KB
    __shared__ int lcnt[128];
    __shared__ int ls[128];
    __shared__ int cur[128];
    int t = threadIdx.x, b = blockIdx.x;
    int base = b * CAP;
    int cnt_b = gcursor[b];                 // relative fill
    if (cnt_b > CAP) cnt_b = CAP;
    int cnt4 = cnt_b >> 2;
    if (t < 128) lcnt[t] = 0;
    {   // int4 staging + scalar tail
        const int4* pb4 = (const int4*)(pairbuf + base);
        for (int k4 = t; k4 < cnt4; k4 += 256) ((int4*)slice)[k4] = pb4[k4];
        int k = (cnt4 << 2) + t;
        if (k < cnt_b) slice[k] = pairbuf[base + k];
    }
    __syncthreads();
    for (int k4 = t; k4 < cnt4; k4 += 256) {
        int4 v = ((const int4*)slice)[k4];
        atomicAdd(&lcnt[(v.x >> 17) & 127], 1);
        atomicAdd(&lcnt[(v.y >> 17) & 127], 1);
        atomicAdd(&lcnt[(v.z >> 17) & 127], 1);
        atomicAdd(&lcnt[(v.w >> 17) & 127], 1);
    }
    {
        int k = (cnt4 << 2) + t;
        if (k < cnt_b) atomicAdd(&lcnt[(slice[k] >> 17) & 127], 1);
    }
    __syncthreads();
    int myc = (t < 128) ? lcnt[t] : 0;
    if (t < 128) ls[t] = myc;
    __syncthreads();
    for (int o = 1; o < 128; o <<= 1) {
        int v = (t < 128 && t >= o) ? ls[t - o] : 0;
        __syncthreads();
        if (t < 128) ls[t] += v;
        __syncthreads();
    }
    int node = (b << 7) + t;
    if (t < 128) {
        int st = base + ls[t] - myc;
        cur[t] = st;
        if (node < N_NODES) {
            rowse[node] = make_int2(st, st + myc);
            float d = rsqrtf((float)(myc + 1));  // +1 self loop
            dinv[node] = d;
            // bufA16[node] = fp16(x[node] * d), 4 halfs (pad 0)
            float x0 = x[node * 3 + 0], x1 = x[node * 3 + 1], x2 = x[node * 3 + 2];
            uint2 u = { pack2(x0 * d, x1 * d), pack2(x2 * d, 0.f) };
            ((uint2*)(bufA16 + (long long)node * 4))[0] = u;
        }
    }
    __syncthreads();
    // in-place sorted write-back (slice fully staged in LDS -> safe)
    for (int k4 = t; k4 < cnt4; k4 += 256) {
        int4 v = ((const int4*)slice)[k4];
        int pos;
        pos = atomicAdd(&cur[(v.x >> 17) & 127], 1); pairbuf[pos] = v.x & 0x1FFFF;
        pos = atomicAdd(&cur[(v.y >> 17) & 127], 1); pairbuf[pos] = v.y & 0x1FFFF;
        pos = atomicAdd(&cur[(v.z >> 17) & 127], 1); pairbuf[pos] = v.z & 0x1FFFF;
        pos = atomicAdd(&cur[(v.w >> 17) & 127], 1); pairbuf[pos] = v.w & 0x1FFFF;
    }
    {
        int k = (cnt4 << 2) + t;
        if (k < cnt_b) {
            int p = slice[k];
            int pos = atomicAdd(&cur[(p >> 17) & 127], 1);
            pairbuf[pos] = p & 0x1FFFF;
        }
    }
}

// ---- K3: gather layer1 (4-wide x rows) + full fused layer1+layer2 transform ----
// 1 lane/node. p = sum(x*dinv); h = relu(d*p@W1 + b1); out16 = fp16((h@W2)*d)
__global__ void k_gather1(const uint2* __restrict__ src16, const int* __restrict__ csr,
                          const int2* __restrict__ rowse, const float* __restrict__ dinv,
                          const float* __restrict__ W1, const float* __restrict__ b1,
                          const float* __restrict__ W2, __half* __restrict__ out16) {
    __shared__ float sW1[48];
    __shared__ float sb1[16];
    __shared__ float sW2[256];
    int t = threadIdx.x;
    sW2[t] = W2[t];
    if (t < 48) sW1[t] = W1[t];
    if (t < 16) sb1[t] = b1[t];
    __syncthreads();
    int node = blockIdx.x * 256 + t;
    if (node >= N_NODES) return;
    int2 se = rowse[node];
    int s = se.x, e = se.y;
    float p[4];
    {
        uint2 u = src16[node];  // self loop (pre-scaled)
        float2 f;
        f = up2(u.x); p[0] = f.x; p[1] = f.y;
        f = up2(u.y); p[2] = f.x; p[3] = f.y;
    }
    int j = s;
    for (; j < e && (j & 3); j++) acc4(p, src16[csr[j]]);  // align
    for (; j + 8 <= e; j += 8) {
        int4 ia = *(const int4*)(csr + j);
        int4 ib = *(const int4*)(csr + j + 4);
        uint2 v0 = src16[ia.x], v1 = src16[ia.y], v2 = src16[ia.z], v3 = src16[ia.w];
        uint2 v4 = src16[ib.x], v5 = src16[ib.y], v6 = src16[ib.z], v7 = src16[ib.w];
        acc4(p, v0); acc4(p, v1); acc4(p, v2); acc4(p, v3);
        acc4(p, v4); acc4(p, v5); acc4(p, v6); acc4(p, v7);
    }
    for (; j < e; j++) acc4(p, src16[csr[j]]);
    float d = dinv[node];
    float q0 = p[0] * d, q1 = p[1] * d, q2 = p[2] * d;
    float h[16];
#pragma unroll
    for (int k = 0; k < 16; k++) {
        float v = q0 * sW1[k] + q1 * sW1[16 + k] + q2 * sW1[32 + k] + sb1[k];
        h[k] = v > 0.f ? v : 0.f;
    }
    float v[16];
#pragma unroll
    for (int jj = 0; jj < 16; jj++) {
        float a = 0.f;
#pragma unroll
        for (int k = 0; k < 16; k++) a += h[k] * sW2[k * 16 + jj];
        v[jj] = a * d;  // prescale for layer 2
    }
    uint4 u0 = { pack2(v[0], v[1]), pack2(v[2], v[3]), pack2(v[4], v[5]), pack2(v[6], v[7]) };
    uint4 u1 = { pack2(v[8], v[9]), pack2(v[10], v[11]), pack2(v[12], v[13]), pack2(v[14], v[15]) };
    uint4* op = (uint4*)(out16 + (long long)node * 16);
    op[0] = u0; op[1] = u1;
}

// ---- K4: gather layer2 + fused pool. 256 thr, 128 nodes, 2 lanes/node, uint4 ----
__global__ void k_gather2(const uint4* __restrict__ src16, const int* __restrict__ csr,
                          const int2* __restrict__ rowse, const float* __restrict__ dinv,
                          const int* __restrict__ batch, float* __restrict__ pooled) {
    __shared__ float pl[8][16];
    __shared__ int ginfo[2];   // gmin, gmax
    int t = threadIdx.x;
    int node0 = blockIdx.x * 128;
    if (t < 128) pl[t >> 4][t & 15] = 0.f;
    if (t == 0) {
        int last = node0 + 127; if (last >= N_NODES) last = N_NODES - 1;
        ginfo[0] = batch[node0];
        ginfo[1] = batch[last];
    }
    __syncthreads();
    int node = node0 + (t >> 1);
    int h = t & 1;
    bool act = node < N_NODES;
    if (act) {
        int2 se = rowse[node];
        int s = se.x, e = se.y;
        float o[8] = {0, 0, 0, 0, 0, 0, 0, 0};
        acc8(o, src16[node * 2 + h]);  // self loop (pre-scaled)
        int j = s;
        for (; j < e && (j & 3); j++) acc8(o, src16[csr[j] * 2 + h]);  // align
        for (; j + 8 <= e; j += 8) {
            int4 ia = *(const int4*)(csr + j);
            int4 ib = *(const int4*)(csr + j + 4);
            uint4 v0 = src16[ia.x * 2 + h], v1 = src16[ia.y * 2 + h];
            uint4 v2 = src16[ia.z * 2 + h], v3 = src16[ia.w * 2 + h];
            uint4 v4 = src16[ib.x * 2 + h], v5 = src16[ib.y * 2 + h];
            uint4 v6 = src16[ib.z * 2 + h], v7 = src16[ib.w * 2 + h];
            acc8(o, v0); acc8(o, v1); acc8(o, v2); acc8(o, v3);
            acc8(o, v4); acc8(o, v5); acc8(o, v6); acc8(o, v7);
        }
        for (; j < e; j++) acc8(o, src16[csr[j] * 2 + h]);
        float d = dinv[node];
#pragma unroll
        for (int k = 0; k < 8; k++) o[k] *= d;
        int slot = batch[node] - ginfo[0];
        if (slot < 8) {
#pragma unroll
            for (int k = 0; k < 8; k++) atomicAdd(&pl[slot][h * 8 + k], o[k]);
        } else {  // pathological span (never expected)
#pragma unroll
            for (int k = 0; k < 8; k++) atomicAdd(&pooled[batch[node] * 16 + h * 8 + k], o[k]);
        }
    }
    __syncthreads();
    if (t < 128) {
        int s = t >> 4, f = t & 15;
        int span = ginfo[1] - ginfo[0];
        if (s <= span && s < 8)
            atomicAdd(&pooled[(ginfo[0] + s) * 16 + f], pl[s][f]);
    }
}

// ---- K5: head: logits = (pooled + cnt*b2) @ Wl + bl; log_softmax ----
__global__ void k_head(const float* __restrict__ pooled, const int* __restrict__ batch,
                       const float* __restrict__ b2, const float* __restrict__ Wl,
                       const float* __restrict__ bl, float* __restrict__ out) {
    int g = blockIdx.x;
    int t = threadIdx.x;  // 64 threads = 1 wave
    __shared__ int range[2];
    __shared__ float pld[16];
    __shared__ float logits[7];
    if (t < 2) {
        int target = g + t;
        int lo = 0, hi = N_NODES;
        while (lo < hi) {
            int mid = (lo + hi) >> 1;
            if (batch[mid] < target) lo = mid + 1; else hi = mid;
        }
        range[t] = lo;
    }
    __syncthreads();
    float cnt = (float)(range[1] - range[0]);
    if (t < 16) pld[t] = pooled[g * 16 + t] + cnt * b2[t];
    __syncthreads();
    if (t < 7) {
        float a = bl[t];
#pragma unroll
        for (int k = 0; k < 16; k++) a += pld[k] * Wl[k * 7 + t];
        logits[t] = a;
    }
    __syncthreads();
    if (t == 0) {
        float m = logits[0];
#pragma unroll
        for (int c = 1; c < 7; c++) m = fmaxf(m, logits[c]);
        float sum = 0.f;
#pragma unroll
        for (int c = 0; c < 7; c++) sum += expf(logits[c] - m);
        float lse = logf(sum) + m;
#pragma unroll
        for (int c = 0; c < 7; c++) out[g * 7 + c] = logits[c] - lse;
    }
}

extern "C" void kernel_launch(void* const* d_in, const int* in_sizes, int n_in,
                              void* d_out, int out_size, void* d_ws, size_t ws_size,
                              hipStream_t stream) {
    const float* x     = (const float*)d_in[0];
    const int*   ei    = (const int*)d_in[1];
    const int*   batch = (const int*)d_in[2];
    const float* W1    = (const float*)d_in[3];
    const float* b1    = (const float*)d_in[4];
    const float* W2    = (const float*)d_in[5];
    const float* b2    = (const float*)d_in[6];
    const float* Wl    = (const float*)d_in[7];
    const float* bl    = (const float*)d_in[8];
    float* out = (float*)d_out;

    const int* row = ei;            // sources
    const int* col = ei + N_EDGES;  // targets

    // ws layout (4-byte words). pairbuf becomes csr in place (k_finalize).
    int*    gcursor = (int*)d_ws;                      // @0        782 (pad 800)
    float*  pooled  = (float*)d_ws + 800;              // @800      16384 (1024*16)
    float*  dinv    = (float*)d_ws + 17200;            // @17200    100000
    int2*   rowse   = (int2*)((int*)d_ws + 117200);    // @117200   200000 words
    int*    pairbuf = (int*)d_ws + 317200;             // @317200   782*4608 = 3603456 (-> csr)
    __half* bufA16  = (__half*)((int*)d_ws + 3920656); // @3920656  200000 words (16B-aligned)
    __half* bufB16  = (__half*)((int*)d_ws + 4120656); // @4120656  800000 words (16B-aligned)

    const int BT = 256;

    hipMemsetAsync(gcursor, 0, 17184 * sizeof(int), stream);  // gcursor + pooled
    k_pair_scatter<<<NPS, BT, 0, stream>>>(row, col, gcursor, pairbuf);
    k_finalize<<<NBUCK, BT, 0, stream>>>(pairbuf, gcursor, rowse, dinv, x, bufA16);
    k_gather1<<<(N_NODES + 255) / 256, BT, 0, stream>>>((const uint2*)bufA16, pairbuf, rowse,
                                                        dinv, W1, b1, W2, bufB16);
    k_gather2<<<(N_NODES + 127) / 128, BT, 0, stream>>>((const uint4*)bufB16, pairbuf, rowse,
                                                        dinv, batch, pooled);
    k_head<<<N_GRAPHS, 64, 0, stream>>>(pooled, batch, b2, Wl, bl, out);
}

// Round 15
// 195.119 us; speedup vs baseline: 1.0687x; 1.0467x over previous
//
#include <hip/hip_runtime.h>
#include <hip/hip_fp16.h>
#include <math.h>

#define N_NODES  100000
#define N_EDGES  3200000
#define N_GRAPHS 1024
#define NBUCK    782          /* buckets of 128 nodes */
#define CAP      4608         /* slots per bucket: mean 4096 + 8 sigma (16B-aligned) */
#define NPS      500          /* pair-scatter blocks */
#define ECH      6400         /* edges per block (500*6400 = 3.2M; 16B-aligned base) */

__device__ inline unsigned pack2(float a, float b) {
    union { __half2 h; unsigned u; } c;
    c.h = __floats2half2_rn(a, b);
    return c.u;
}
__device__ inline float2 up2(unsigned u) {
    union { unsigned u; __half2 h; } c; c.u = u;
    return __half22float2(c.h);
}
__device__ inline void acc4(float* a, uint2 v) {
    float2 f;
    f = up2(v.x); a[0] += f.x; a[1] += f.y;
    f = up2(v.y); a[2] += f.x; a[3] += f.y;
}

// ---- K1: pair scatter, int4 streams, in-LDS bucket sort + burst copy-out ----
// (R12's proven version: two passes over col; 2nd pass hits LLC, costs no HBM)
// pack = src | (dst&127)<<17 ; bucket = dst>>7
__global__ void k_pair_scatter(const int* __restrict__ row, const int* __restrict__ col,
                               int* __restrict__ gcursor, int* __restrict__ pairbuf) {
    __shared__ int            sbuf[ECH];    // 25.6 KB
    __shared__ unsigned short sbk[ECH];     // 12.8 KB
    __shared__ int            lhist[NBUCK]; // counts -> wbase (reused)
    __shared__ int            lcur[NBUCK];
    int t = threadIdx.x;
    int e0 = blockIdx.x * ECH;
    const int4* col4 = (const int4*)(col + e0);
    const int4* row4 = (const int4*)(row + e0);
    for (int j = t; j < NBUCK; j += 256) lhist[j] = 0;
    __syncthreads();
    // pass 1: histogram, 4 edges/lane/iter
    for (int k = t; k < ECH / 4; k += 256) {
        int4 c = col4[k];
        atomicAdd(&lhist[c.x >> 7], 1);
        atomicAdd(&lhist[c.y >> 7], 1);
        atomicAdd(&lhist[c.z >> 7], 1);
        atomicAdd(&lhist[c.w >> 7], 1);
    }
    __syncthreads();
    if (t < 64) {  // wave-0 shuffle scan -> exclusive prefix in lcur
        int carry = 0;
        for (int c0 = 0; c0 < NBUCK; c0 += 64) {
            int idx = c0 + t;
            int v = (idx < NBUCK) ? lhist[idx] : 0;
            int orig = v;
#pragma unroll
            for (int o = 1; o < 64; o <<= 1) {
                int u = __shfl_up(v, o, 64);
                if (t >= o) v += u;
            }
            if (idx < NBUCK) lcur[idx] = v - orig + carry;
            carry += __shfl(v, 63, 64);
        }
    }
    __syncthreads();
    // reserve global chunks; lhist becomes wbase
    for (int j = t; j < NBUCK; j += 256) {
        int c = lhist[j];
        int g = c ? atomicAdd(&gcursor[j], c) : 0;  // relative offset in bucket
        lhist[j] = j * CAP + g - lcur[j];
    }
    __syncthreads();
    // pass 2: place edges bucket-sorted in LDS, 4 edges/lane/iter
    for (int k = t; k < ECH / 4; k += 256) {
        int4 c = col4[k];
        int4 r = row4[k];
        int bk, pos;
        bk = c.x >> 7; pos = atomicAdd(&lcur[bk], 1);
        sbuf[pos] = r.x | ((c.x & 127) << 17); sbk[pos] = (unsigned short)bk;
        bk = c.y >> 7; pos = atomicAdd(&lcur[bk], 1);
        sbuf[pos] = r.y | ((c.y & 127) << 17); sbk[pos] = (unsigned short)bk;
        bk = c.z >> 7; pos = atomicAdd(&lcur[bk], 1);
        sbuf[pos] = r.z | ((c.z & 127) << 17); sbk[pos] = (unsigned short)bk;
        bk = c.w >> 7; pos = atomicAdd(&lcur[bk], 1);
        sbuf[pos] = r.w | ((c.w & 127) << 17); sbk[pos] = (unsigned short)bk;
    }
    __syncthreads();
    // burst copy-out: b128 LDS reads, coalesced sequential stores per chunk
    for (int k4 = t; k4 < ECH / 4; k4 += 256) {
        int k = k4 << 2;
        int4 v = ((const int4*)sbuf)[k4];
        ushort4 bb = ((const ushort4*)sbk)[k4];
        int p0 = lhist[bb.x] + k;
        int p1 = lhist[bb.y] + k + 1;
        int p2 = lhist[bb.z] + k + 2;
        int p3 = lhist[bb.w] + k + 3;
        if (p0 < (bb.x + 1) * CAP) pairbuf[p0] = v.x;  // overflow guards (never expected)
        if (p1 < (bb.y + 1) * CAP) pairbuf[p1] = v.y;
        if (p2 < (bb.z + 1) * CAP) pairbuf[p2] = v.z;
        if (p3 < (bb.w + 1) * CAP) pairbuf[p3] = v.w;
    }
}

// ---- K2: per-bucket CSR finalize IN PLACE + dinv + bufA16 = fp16(x*dinv) [4 halfs] ----
__global__ void k_finalize(int* __restrict__ pairbuf, const int* __restrict__ gcursor,
                           int2* __restrict__ rowse, float* __restrict__ dinv,
                           const float* __restrict__ x, __half* __restrict__ bufA16) {
    __shared__ int slice[CAP];   // 18.4 KB
    __shared__ int lcnt[128];
    __shared__ int ls[128];
    __shared__ int cur[128];
    int t = threadIdx.x, b = blockIdx.x;
    int base = b * CAP;
    int cnt_b = gcursor[b];                 // relative fill
    if (cnt_b > CAP) cnt_b = CAP;
    int cnt4 = cnt_b >> 2;
    if (t < 128) lcnt[t] = 0;
    {   // int4 staging + scalar tail
        const int4* pb4 = (const int4*)(pairbuf + base);
        for (int k4 = t; k4 < cnt4; k4 += 256) ((int4*)slice)[k4] = pb4[k4];
        int k = (cnt4 << 2) + t;
        if (k < cnt_b) slice[k] = pairbuf[base + k];
    }
    __syncthreads();
    for (int k4 = t; k4 < cnt4; k4 += 256) {
        int4 v = ((const int4*)slice)[k4];
        atomicAdd(&lcnt[(v.x >> 17) & 127], 1);
        atomicAdd(&lcnt[(v.y >> 17) & 127], 1);
        atomicAdd(&lcnt[(v.z >> 17) & 127], 1);
        atomicAdd(&lcnt[(v.w >> 17) & 127], 1);
    }
    {
        int k = (cnt4 << 2) + t;
        if (k < cnt_b) atomicAdd(&lcnt[(slice[k] >> 17) & 127], 1);
    }
    __syncthreads();
    int myc = (t < 128) ? lcnt[t] : 0;
    if (t < 128) ls[t] = myc;
    __syncthreads();
    for (int o = 1; o < 128; o <<= 1) {
        int v = (t < 128 && t >= o) ? ls[t - o] : 0;
        __syncthreads();
        if (t < 128) ls[t] += v;
        __syncthreads();
    }
    int node = (b << 7) + t;
    if (t < 128) {
        int st = base + ls[t] - myc;
        cur[t] = st;
        if (node < N_NODES) {
            rowse[node] = make_int2(st, st + myc);
            float d = rsqrtf((float)(myc + 1));  // +1 self loop
            dinv[node] = d;
            // bufA16[node] = fp16(x[node] * d), 4 halfs (pad 0)
            float x0 = x[node * 3 + 0], x1 = x[node * 3 + 1], x2 = x[node * 3 + 2];
            uint2 u = { pack2(x0 * d, x1 * d), pack2(x2 * d, 0.f) };
            ((uint2*)(bufA16 + (long long)node * 4))[0] = u;
        }
    }
    __syncthreads();
    // in-place sorted write-back (slice fully staged in LDS -> safe)
    for (int k4 = t; k4 < cnt4; k4 += 256) {
        int4 v = ((const int4*)slice)[k4];
        int pos;
        pos = atomicAdd(&cur[(v.x >> 17) & 127], 1); pairbuf[pos] = v.x & 0x1FFFF;
        pos = atomicAdd(&cur[(v.y >> 17) & 127], 1); pairbuf[pos] = v.y & 0x1FFFF;
        pos = atomicAdd(&cur[(v.z >> 17) & 127], 1); pairbuf[pos] = v.z & 0x1FFFF;
        pos = atomicAdd(&cur[(v.w >> 17) & 127], 1); pairbuf[pos] = v.w & 0x1FFFF;
    }
    {
        int k = (cnt4 << 2) + t;
        if (k < cnt_b) {
            int p = slice[k];
            int pos = atomicAdd(&cur[(p >> 17) & 127], 1);
            pairbuf[pos] = p & 0x1FFFF;
        }
    }
}

// ---- K3: gather layer1 (4-wide x rows) + full fused layer1+layer2 transform ----
// 1 lane/node, 16-deep MLP. p = sum(x*dinv); h = relu(d*p@W1+b1); out = fp16((h@W2)*d)
__global__ void k_gather1(const uint2* __restrict__ src16, const int* __restrict__ csr,
                          const int2* __restrict__ rowse, const float* __restrict__ dinv,
                          const float* __restrict__ W1, const float* __restrict__ b1,
                          const float* __restrict__ W2, __half* __restrict__ out16) {
    __shared__ float sW1[48];
    __shared__ float sb1[16];
    __shared__ float sW2[256];
    int t = threadIdx.x;
    sW2[t] = W2[t];
    if (t < 48) sW1[t] = W1[t];
    if (t < 16) sb1[t] = b1[t];
    __syncthreads();
    int node = blockIdx.x * 256 + t;
    if (node >= N_NODES) return;
    int2 se = rowse[node];
    int s = se.x, e = se.y;
    float p[4];
    {
        uint2 u = src16[node];  // self loop (pre-scaled)
        float2 f;
        f = up2(u.x); p[0] = f.x; p[1] = f.y;
        f = up2(u.y); p[2] = f.x; p[3] = f.y;
    }
    int j = s;
    for (; j < e && (j & 3); j++) acc4(p, src16[csr[j]]);  // align
    for (; j + 16 <= e; j += 16) {  // 16 independent gathers in flight
        int4 ia = *(const int4*)(csr + j);
        int4 ib = *(const int4*)(csr + j + 4);
        int4 ic = *(const int4*)(csr + j + 8);
        int4 id = *(const int4*)(csr + j + 12);
        uint2 v0 = src16[ia.x], v1 = src16[ia.y], v2 = src16[ia.z], v3 = src16[ia.w];
        uint2 v4 = src16[ib.x], v5 = src16[ib.y], v6 = src16[ib.z], v7 = src16[ib.w];
        uint2 v8 = src16[ic.x], v9 = src16[ic.y], va = src16[ic.z], vb = src16[ic.w];
        uint2 vc = src16[id.x], vd = src16[id.y], ve = src16[id.z], vf = src16[id.w];
        acc4(p, v0); acc4(p, v1); acc4(p, v2); acc4(p, v3);
        acc4(p, v4); acc4(p, v5); acc4(p, v6); acc4(p, v7);
        acc4(p, v8); acc4(p, v9); acc4(p, va); acc4(p, vb);
        acc4(p, vc); acc4(p, vd); acc4(p, ve); acc4(p, vf);
    }
    for (; j + 8 <= e; j += 8) {
        int4 ia = *(const int4*)(csr + j);
        int4 ib = *(const int4*)(csr + j + 4);
        uint2 v0 = src16[ia.x], v1 = src16[ia.y], v2 = src16[ia.z], v3 = src16[ia.w];
        uint2 v4 = src16[ib.x], v5 = src16[ib.y], v6 = src16[ib.z], v7 = src16[ib.w];
        acc4(p, v0); acc4(p, v1); acc4(p, v2); acc4(p, v3);
        acc4(p, v4); acc4(p, v5); acc4(p, v6); acc4(p, v7);
    }
    for (; j < e; j++) acc4(p, src16[csr[j]]);
    float d = dinv[node];
    float q0 = p[0] * d, q1 = p[1] * d, q2 = p[2] * d;
    float h[16];
#pragma unroll
    for (int k = 0; k < 16; k++) {
        float v = q0 * sW1[k] + q1 * sW1[16 + k] + q2 * sW1[32 + k] + sb1[k];
        h[k] = v > 0.f ? v : 0.f;
    }
    float v[16];
#pragma unroll
    for (int jj = 0; jj < 16; jj++) {
        float a = 0.f;
#pragma unroll
        for (int k = 0; k < 16; k++) a += h[k] * sW2[k * 16 + jj];
        v[jj] = a * d;  // prescale for layer 2
    }
    uint4 u0 = { pack2(v[0], v[1]), pack2(v[2], v[3]), pack2(v[4], v[5]), pack2(v[6], v[7]) };
    uint4 u1 = { pack2(v[8], v[9]), pack2(v[10], v[11]), pack2(v[12], v[13]), pack2(v[14], v[15]) };
    uint4* op = (uint4*)(out16 + (long long)node * 16);
    op[0] = u0; op[1] = u1;
}

// ---- K4: gather layer2 + fused global-add-pool. 256 thr, 64 nodes, 4 lanes ----
// (R12's proven version)
__global__ void k_gather2(const uint2* __restrict__ src16, const int* __restrict__ csr,
                          const int2* __restrict__ rowse, const float* __restrict__ dinv,
                          const int* __restrict__ batch, float* __restrict__ pooled) {
    __shared__ float pl[8][16];
    __shared__ int ginfo[2];   // gmin, gmax
    int t = threadIdx.x;
    int node0 = blockIdx.x * 64;
    if (t < 128) pl[t >> 4][t & 15] = 0.f;
    if (t == 0) {
        int last = node0 + 63; if (last >= N_NODES) last = N_NODES - 1;
        ginfo[0] = batch[node0];
        ginfo[1] = batch[last];
    }
    __syncthreads();
    int node = node0 + (t >> 2);
    int h = t & 3;
    float o[4] = {0, 0, 0, 0};
    bool act = node < N_NODES;
    if (act) {
        int2 se = rowse[node];
        int s = se.x, e = se.y;
        uint2 u = src16[node * 4 + h];
        float2 f;
        f = up2(u.x); o[0] = f.x; o[1] = f.y;
        f = up2(u.y); o[2] = f.x; o[3] = f.y;
        int j = s;
        for (; j < e && (j & 3); j++) acc4(o, src16[csr[j] * 4 + h]);  // align
        for (; j + 8 <= e; j += 8) {
            int4 ia = *(const int4*)(csr + j);
            int4 ib = *(const int4*)(csr + j + 4);
            uint2 v0 = src16[ia.x * 4 + h], v1 = src16[ia.y * 4 + h];
            uint2 v2 = src16[ia.z * 4 + h], v3 = src16[ia.w * 4 + h];
            uint2 v4 = src16[ib.x * 4 + h], v5 = src16[ib.y * 4 + h];
            uint2 v6 = src16[ib.z * 4 + h], v7 = src16[ib.w * 4 + h];
            acc4(o, v0); acc4(o, v1); acc4(o, v2); acc4(o, v3);
            acc4(o, v4); acc4(o, v5); acc4(o, v6); acc4(o, v7);
        }
        for (; j < e; j++) acc4(o, src16[csr[j] * 4 + h]);
        float d = dinv[node];
        o[0] *= d; o[1] *= d; o[2] *= d; o[3] *= d;
        int slot = batch[node] - ginfo[0];
        if (slot < 8) {
#pragma unroll
            for (int k = 0; k < 4; k++) atomicAdd(&pl[slot][h * 4 + k], o[k]);
        } else {  // pathological span (never expected)
#pragma unroll
            for (int k = 0; k < 4; k++) atomicAdd(&pooled[batch[node] * 16 + h * 4 + k], o[k]);
        }
    }
    __syncthreads();
    if (t < 128) {
        int s = t >> 4, f = t & 15;
        int span = ginfo[1] - ginfo[0];
        if (s <= span && s < 8)
            atomicAdd(&pooled[(ginfo[0] + s) * 16 + f], pl[s][f]);
    }
}

// ---- K5: head: logits = (pooled + cnt*b2) @ Wl + bl; log_softmax ----
__global__ void k_head(const float* __restrict__ pooled, const int* __restrict__ batch,
                       const float* __restrict__ b2, const float* __restrict__ Wl,
                       const float* __restrict__ bl, float* __restrict__ out) {
    int g = blockIdx.x;
    int t = threadIdx.x;  // 64 threads = 1 wave
    __shared__ int range[2];
    __shared__ float pld[16];
    __shared__ float logits[7];
    if (t < 2) {
        int target = g + t;
        int lo = 0, hi = N_NODES;
        while (lo < hi) {
            int mid = (lo + hi) >> 1;
            if (batch[mid] < target) lo = mid + 1; else hi = mid;
        }
        range[t] = lo;
    }
    __syncthreads();
    float cnt = (float)(range[1] - range[0]);
    if (t < 16) pld[t] = pooled[g * 16 + t] + cnt * b2[t];
    __syncthreads();
    if (t < 7) {
        float a = bl[t];
#pragma unroll
        for (int k = 0; k < 16; k++) a += pld[k] * Wl[k * 7 + t];
        logits[t] = a;
    }
    __syncthreads();
    if (t == 0) {
        float m = logits[0];
#pragma unroll
        for (int c = 1; c < 7; c++) m = fmaxf(m, logits[c]);
        float sum = 0.f;
#pragma unroll
        for (int c = 0; c < 7; c++) sum += expf(logits[c] - m);
        float lse = logf(sum) + m;
#pragma unroll
        for (int c = 0; c < 7; c++) out[g * 7 + c] = logits[c] - lse;
    }
}

extern "C" void kernel_launch(void* const* d_in, const int* in_sizes, int n_in,
                              void* d_out, int out_size, void* d_ws, size_t ws_size,
                              hipStream_t stream) {
    const float* x     = (const float*)d_in[0];
    const int*   ei    = (const int*)d_in[1];
    const int*   batch = (const int*)d_in[2];
    const float* W1    = (const float*)d_in[3];
    const float* b1    = (const float*)d_in[4];
    const float* W2    = (const float*)d_in[5];
    const float* b2    = (const float*)d_in[6];
    const float* Wl    = (const float*)d_in[7];
    const float* bl    = (const float*)d_in[8];
    float* out = (float*)d_out;

    const int* row = ei;            // sources
    const int* col = ei + N_EDGES;  // targets

    // ws layout (4-byte words). pairbuf becomes csr in place (k_finalize).
    int*    gcursor = (int*)d_ws;                      // @0        782 (pad 800)
    float*  pooled  = (float*)d_ws + 800;              // @800      16384 (1024*16)
    float*  dinv    = (float*)d_ws + 17200;            // @17200    100000
    int2*   rowse   = (int2*)((int*)d_ws + 117200);    // @117200   200000 words
    int*    pairbuf = (int*)d_ws + 317200;             // @317200   782*4608 = 3603456 (-> csr)
    __half* bufA16  = (__half*)((int*)d_ws + 3920656); // @3920656  200000 words (16B-aligned)
    __half* bufB16  = (__half*)((int*)d_ws + 4120656); // @4120656  800000 words (16B-aligned)

    const int BT = 256;

    hipMemsetAsync(gcursor, 0, 17184 * sizeof(int), stream);  // gcursor + pooled
    k_pair_scatter<<<NPS, BT, 0, stream>>>(row, col, gcursor, pairbuf);
    k_finalize<<<NBUCK, BT, 0, stream>>>(pairbuf, gcursor, rowse, dinv, x, bufA16);
    k_gather1<<<(N_NODES + 255) / 256, BT, 0, stream>>>((const uint2*)bufA16, pairbuf, rowse,
                                                        dinv, W1, b1, W2, bufB16);
    k_gather2<<<(N_NODES + 63) / 64, BT, 0, stream>>>((const uint2*)bufB16, pairbuf, rowse,
                                                      dinv, batch, pooled);
    k_head<<<N_GRAPHS, 64, 0, stream>>>(pooled, batch, b2, Wl, bl, out);
}

// Round 16
// 194.958 us; speedup vs baseline: 1.0696x; 1.0008x over previous
//
#include <hip/hip_runtime.h>
#include <hip/hip_fp16.h>
#include <math.h>

#define N_NODES  100000
#define N_EDGES  3200000
#define N_GRAPHS 1024
#define NBUCK    782          /* buckets of 128 nodes */
#define CAP      4608         /* slots per bucket: mean 4096 + 8 sigma (16B-aligned) */
#define NPS      500          /* pair-scatter blocks */
#define ECH      6400         /* edges per block (500*6400 = 3.2M; 16B-aligned base) */

__device__ inline unsigned pack2(float a, float b) {
    union { __half2 h; unsigned u; } c;
    c.h = __floats2half2_rn(a, b);
    return c.u;
}
__device__ inline float2 up2(unsigned u) {
    union { unsigned u; __half2 h; } c; c.u = u;
    return __half22float2(c.h);
}
__device__ inline void acc4(float* a, uint2 v) {
    float2 f;
    f = up2(v.x); a[0] += f.x; a[1] += f.y;
    f = up2(v.y); a[2] += f.x; a[3] += f.y;
}

// ---- K1: pair scatter, int4 streams, in-LDS bucket sort + burst copy-out ----
// pack = src | (dst&127)<<17 ; bucket = dst>>7
__global__ void k_pair_scatter(const int* __restrict__ row, const int* __restrict__ col,
                               int* __restrict__ gcursor, int* __restrict__ pairbuf) {
    __shared__ int            sbuf[ECH];    // 25.6 KB
    __shared__ unsigned short sbk[ECH];     // 12.8 KB
    __shared__ int            lhist[NBUCK]; // counts -> wbase (reused)
    __shared__ int            lcur[NBUCK];
    int t = threadIdx.x;
    int e0 = blockIdx.x * ECH;
    const int4* col4 = (const int4*)(col + e0);
    const int4* row4 = (const int4*)(row + e0);
    for (int j = t; j < NBUCK; j += 256) lhist[j] = 0;
    __syncthreads();
    // pass 1: histogram, 4 edges/lane/iter
    for (int k = t; k < ECH / 4; k += 256) {
        int4 c = col4[k];
        atomicAdd(&lhist[c.x >> 7], 1);
        atomicAdd(&lhist[c.y >> 7], 1);
        atomicAdd(&lhist[c.z >> 7], 1);
        atomicAdd(&lhist[c.w >> 7], 1);
    }
    __syncthreads();
    if (t < 64) {  // wave-0 shuffle scan -> exclusive prefix in lcur
        int carry = 0;
        for (int c0 = 0; c0 < NBUCK; c0 += 64) {
            int idx = c0 + t;
            int v = (idx < NBUCK) ? lhist[idx] : 0;
            int orig = v;
#pragma unroll
            for (int o = 1; o < 64; o <<= 1) {
                int u = __shfl_up(v, o, 64);
                if (t >= o) v += u;
            }
            if (idx < NBUCK) lcur[idx] = v - orig + carry;
            carry += __shfl(v, 63, 64);
        }
    }
    __syncthreads();
    // reserve global chunks; lhist becomes wbase
    for (int j = t; j < NBUCK; j += 256) {
        int c = lhist[j];
        int g = c ? atomicAdd(&gcursor[j], c) : 0;  // relative offset in bucket
        lhist[j] = j * CAP + g - lcur[j];
    }
    __syncthreads();
    // pass 2: place edges bucket-sorted in LDS, 4 edges/lane/iter
    for (int k = t; k < ECH / 4; k += 256) {
        int4 c = col4[k];
        int4 r = row4[k];
        int bk, pos;
        bk = c.x >> 7; pos = atomicAdd(&lcur[bk], 1);
        sbuf[pos] = r.x | ((c.x & 127) << 17); sbk[pos] = (unsigned short)bk;
        bk = c.y >> 7; pos = atomicAdd(&lcur[bk], 1);
        sbuf[pos] = r.y | ((c.y & 127) << 17); sbk[pos] = (unsigned short)bk;
        bk = c.z >> 7; pos = atomicAdd(&lcur[bk], 1);
        sbuf[pos] = r.z | ((c.z & 127) << 17); sbk[pos] = (unsigned short)bk;
        bk = c.w >> 7; pos = atomicAdd(&lcur[bk], 1);
        sbuf[pos] = r.w | ((c.w & 127) << 17); sbk[pos] = (unsigned short)bk;
    }
    __syncthreads();
    // burst copy-out: b128 LDS reads, coalesced sequential stores per chunk
    for (int k4 = t; k4 < ECH / 4; k4 += 256) {
        int k = k4 << 2;
        int4 v = ((const int4*)sbuf)[k4];
        ushort4 bb = ((const ushort4*)sbk)[k4];
        int p0 = lhist[bb.x] + k;
        int p1 = lhist[bb.y] + k + 1;
        int p2 = lhist[bb.z] + k + 2;
        int p3 = lhist[bb.w] + k + 3;
        if (p0 < (bb.x + 1) * CAP) pairbuf[p0] = v.x;  // overflow guards (never expected)
        if (p1 < (bb.y + 1) * CAP) pairbuf[p1] = v.y;
        if (p2 < (bb.z + 1) * CAP) pairbuf[p2] = v.z;
        if (p3 < (bb.w + 1) * CAP) pairbuf[p3] = v.w;
    }
}

// ---- K2: per-bucket CSR finalize IN PLACE + dinv + bufA16 = fp16(x*dinv) [4 halfs] ----
__global__ void k_finalize(int* __restrict__ pairbuf, const int* __restrict__ gcursor,
                           int2* __restrict__ rowse, float* __restrict__ dinv,
                           const float* __restrict__ x, __half* __restrict__ bufA16) {
    __shared__ int slice[CAP];   // 18.4 KB
    __shared__ int lcnt[128];
    __shared__ int ls[128];
    __shared__ int cur[128];
    int t = threadIdx.x, b = blockIdx.x;
    int base = b * CAP;
    int cnt_b = gcursor[b];                 // relative fill
    if (cnt_b > CAP) cnt_b = CAP;
    int cnt4 = cnt_b >> 2;
    if (t < 128) lcnt[t] = 0;
    {   // int4 staging + scalar tail
        const int4* pb4 = (const int4*)(pairbuf + base);
        for (int k4 = t; k4 < cnt4; k4 += 256) ((int4*)slice)[k4] = pb4[k4];
        int k = (cnt4 << 2) + t;
        if (k < cnt_b) slice[k] = pairbuf[base + k];
    }
    __syncthreads();
    for (int k4 = t; k4 < cnt4; k4 += 256) {
        int4 v = ((const int4*)slice)[k4];
        atomicAdd(&lcnt[(v.x >> 17) & 127], 1);
        atomicAdd(&lcnt[(v.y >> 17) & 127], 1);
        atomicAdd(&lcnt[(v.z >> 17) & 127], 1);
        atomicAdd(&lcnt[(v.w >> 17) & 127], 1);
    }
    {
        int k = (cnt4 << 2) + t;
        if (k < cnt_b) atomicAdd(&lcnt[(slice[k] >> 17) & 127], 1);
    }
    __syncthreads();
    int myc = (t < 128) ? lcnt[t] : 0;
    if (t < 128) ls[t] = myc;
    __syncthreads();
    for (int o = 1; o < 128; o <<= 1) {
        int v = (t < 128 && t >= o) ? ls[t - o] : 0;
        __syncthreads();
        if (t < 128) ls[t] += v;
        __syncthreads();
    }
    int node = (b << 7) + t;
    if (t < 128) {
        int st = base + ls[t] - myc;
        cur[t] = st;
        if (node < N_NODES) {
            rowse[node] = make_int2(st, st + myc);
            float d = rsqrtf((float)(myc + 1));  // +1 self loop
            dinv[node] = d;
            // bufA16[node] = fp16(x[node] * d), 4 halfs (pad 0)
            float x0 = x[node * 3 + 0], x1 = x[node * 3 + 1], x2 = x[node * 3 + 2];
            uint2 u = { pack2(x0 * d, x1 * d), pack2(x2 * d, 0.f) };
            ((uint2*)(bufA16 + (long long)node * 4))[0] = u;
        }
    }
    __syncthreads();
    // in-place sorted write-back (slice fully staged in LDS -> safe)
    for (int k4 = t; k4 < cnt4; k4 += 256) {
        int4 v = ((const int4*)slice)[k4];
        int pos;
        pos = atomicAdd(&cur[(v.x >> 17) & 127], 1); pairbuf[pos] = v.x & 0x1FFFF;
        pos = atomicAdd(&cur[(v.y >> 17) & 127], 1); pairbuf[pos] = v.y & 0x1FFFF;
        pos = atomicAdd(&cur[(v.z >> 17) & 127], 1); pairbuf[pos] = v.z & 0x1FFFF;
        pos = atomicAdd(&cur[(v.w >> 17) & 127], 1); pairbuf[pos] = v.w & 0x1FFFF;
    }
    {
        int k = (cnt4 << 2) + t;
        if (k < cnt_b) {
            int p = slice[k];
            int pos = atomicAdd(&cur[(p >> 17) & 127], 1);
            pairbuf[pos] = p & 0x1FFFF;
        }
    }
}

// ---- K3: gather layer1, 2 lanes/node (parity-interleaved int4 groups), fused L1+L2 ----
__global__ void k_gather1(const uint2* __restrict__ src16, const int* __restrict__ csr,
                          const int2* __restrict__ rowse, const float* __restrict__ dinv,
                          const float* __restrict__ W1, const float* __restrict__ b1,
                          const float* __restrict__ W2, __half* __restrict__ out16) {
    __shared__ float sW1[48];
    __shared__ float sb1[16];
    __shared__ float sW2[256];
    int t = threadIdx.x;
    sW2[t] = W2[t];
    if (t < 48) sW1[t] = W1[t];
    if (t < 16) sb1[t] = b1[t];
    __syncthreads();
    int local = t >> 1, h = t & 1;
    int node = blockIdx.x * 128 + local;
    if (node >= N_NODES) return;
    int2 se = rowse[node];
    int s = se.x, e = se.y;
    float p[4] = {0.f, 0.f, 0.f, 0.f};
    if (h == 0) {
        uint2 u = src16[node];  // self loop (pre-scaled)
        float2 f;
        f = up2(u.x); p[0] = f.x; p[1] = f.y;
        f = up2(u.y); p[2] = f.x; p[3] = f.y;
    }
    int ja = (s + 3) & ~3;           // first 16B-aligned csr index
    if (ja > e) ja = e;
    if (h == 0)                       // scalar prologue on lane 0
        for (int j = s; j < ja; j++) acc4(p, src16[csr[j]]);
    int nfull = ((e - ja) >> 4) << 4; // whole 16-edge super-groups
    // lane h covers int4 groups at offsets {h*4, h*4+8} within each 16-stride
    for (int jj = ja + h * 4; jj < ja + nfull; jj += 16) {
        int4 ia = *(const int4*)(csr + jj);
        int4 ib = *(const int4*)(csr + jj + 8);
        uint2 v0 = src16[ia.x], v1 = src16[ia.y], v2 = src16[ia.z], v3 = src16[ia.w];
        uint2 v4 = src16[ib.x], v5 = src16[ib.y], v6 = src16[ib.z], v7 = src16[ib.w];
        acc4(p, v0); acc4(p, v1); acc4(p, v2); acc4(p, v3);
        acc4(p, v4); acc4(p, v5); acc4(p, v6); acc4(p, v7);
    }
    for (int j = ja + nfull + h; j < e; j += 2)  // interleaved scalar tail
        acc4(p, src16[csr[j]]);
    // combine the two lanes
#pragma unroll
    for (int k = 0; k < 4; k++) p[k] += __shfl_xor(p[k], 1);
    float d = dinv[node];
    float q0 = p[0] * d, q1 = p[1] * d, q2 = p[2] * d;
    float hv[16];
#pragma unroll
    for (int k = 0; k < 16; k++) {
        float v = q0 * sW1[k] + q1 * sW1[16 + k] + q2 * sW1[32 + k] + sb1[k];
        hv[k] = v > 0.f ? v : 0.f;
    }
    float v[8];
#pragma unroll
    for (int jj = 0; jj < 8; jj++) {
        int jo = h * 8 + jj;
        float a = 0.f;
#pragma unroll
        for (int k = 0; k < 16; k++) a += hv[k] * sW2[k * 16 + jo];
        v[jj] = a * d;  // prescale for layer 2
    }
    uint4 u = { pack2(v[0], v[1]), pack2(v[2], v[3]), pack2(v[4], v[5]), pack2(v[6], v[7]) };
    ((uint4*)(out16 + (long long)node * 16 + h * 8))[0] = u;
}

// ---- K4: gather layer2 + fused pool. 256 thr, 64 nodes, 4 lanes, 16-deep MLP ----
__global__ void k_gather2(const uint2* __restrict__ src16, const int* __restrict__ csr,
                          const int2* __restrict__ rowse, const float* __restrict__ dinv,
                          const int* __restrict__ batch, float* __restrict__ pooled) {
    __shared__ float pl[8][16];
    __shared__ int ginfo[2];   // gmin, gmax
    int t = threadIdx.x;
    int node0 = blockIdx.x * 64;
    if (t < 128) pl[t >> 4][t & 15] = 0.f;
    if (t == 0) {
        int last = node0 + 63; if (last >= N_NODES) last = N_NODES - 1;
        ginfo[0] = batch[node0];
        ginfo[1] = batch[last];
    }
    __syncthreads();
    int node = node0 + (t >> 2);
    int h = t & 3;
    float o[4] = {0, 0, 0, 0};
    bool act = node < N_NODES;
    if (act) {
        int2 se = rowse[node];
        int s = se.x, e = se.y;
        uint2 u = src16[node * 4 + h];
        float2 f;
        f = up2(u.x); o[0] = f.x; o[1] = f.y;
        f = up2(u.y); o[2] = f.x; o[3] = f.y;
        int j = s;
        for (; j < e && (j & 3); j++) acc4(o, src16[csr[j] * 4 + h]);  // align
        for (; j + 16 <= e; j += 16) {  // 16 independent gathers in flight
            int4 ia = *(const int4*)(csr + j);
            int4 ib = *(const int4*)(csr + j + 4);
            int4 ic = *(const int4*)(csr + j + 8);
            int4 id = *(const int4*)(csr + j + 12);
            uint2 v0 = src16[ia.x * 4 + h], v1 = src16[ia.y * 4 + h];
            uint2 v2 = src16[ia.z * 4 + h], v3 = src16[ia.w * 4 + h];
            uint2 v4 = src16[ib.x * 4 + h], v5 = src16[ib.y * 4 + h];
            uint2 v6 = src16[ib.z * 4 + h], v7 = src16[ib.w * 4 + h];
            uint2 v8 = src16[ic.x * 4 + h], v9 = src16[ic.y * 4 + h];
            uint2 va = src16[ic.z * 4 + h], vb = src16[ic.w * 4 + h];
            uint2 vc = src16[id.x * 4 + h], vd = src16[id.y * 4 + h];
            uint2 ve = src16[id.z * 4 + h], vf = src16[id.w * 4 + h];
            acc4(o, v0); acc4(o, v1); acc4(o, v2); acc4(o, v3);
            acc4(o, v4); acc4(o, v5); acc4(o, v6); acc4(o, v7);
            acc4(o, v8); acc4(o, v9); acc4(o, va); acc4(o, vb);
            acc4(o, vc); acc4(o, vd); acc4(o, ve); acc4(o, vf);
        }
        for (; j + 8 <= e; j += 8) {
            int4 ia = *(const int4*)(csr + j);
            int4 ib = *(const int4*)(csr + j + 4);
            uint2 v0 = src16[ia.x * 4 + h], v1 = src16[ia.y * 4 + h];
            uint2 v2 = src16[ia.z * 4 + h], v3 = src16[ia.w * 4 + h];
            uint2 v4 = src16[ib.x * 4 + h], v5 = src16[ib.y * 4 + h];
            uint2 v6 = src16[ib.z * 4 + h], v7 = src16[ib.w * 4 + h];
            acc4(o, v0); acc4(o, v1); acc4(o, v2); acc4(o, v3);
            acc4(o, v4); acc4(o, v5); acc4(o, v6); acc4(o, v7);
        }
        for (; j < e; j++) acc4(o, src16[csr[j] * 4 + h]);
        float d = dinv[node];
        o[0] *= d; o[1] *= d; o[2] *= d; o[3] *= d;
        int slot = batch[node] - ginfo[0];
        if (slot < 8) {
#pragma unroll
            for (int k = 0; k < 4; k++) atomicAdd(&pl[slot][h * 4 + k], o[k]);
        } else {  // pathological span (never expected)
#pragma unroll
            for (int k = 0; k < 4; k++) atomicAdd(&pooled[batch[node] * 16 + h * 4 + k], o[k]);
        }
    }
    __syncthreads();
    if (t < 128) {
        int s = t >> 4, f = t & 15;
        int span = ginfo[1] - ginfo[0];
        if (s <= span && s < 8)
            atomicAdd(&pooled[(ginfo[0] + s) * 16 + f], pl[s][f]);
    }
}

// ---- K5: head: logits = (pooled + cnt*b2) @ Wl + bl; log_softmax ----
__global__ void k_head(const float* __restrict__ pooled, const int* __restrict__ batch,
                       const float* __restrict__ b2, const float* __restrict__ Wl,
                       const float* __restrict__ bl, float* __restrict__ out) {
    int g = blockIdx.x;
    int t = threadIdx.x;  // 64 threads = 1 wave
    __shared__ int range[2];
    __shared__ float pld[16];
    __shared__ float logits[7];
    if (t < 2) {
        int target = g + t;
        int lo = 0, hi = N_NODES;
        while (lo < hi) {
            int mid = (lo + hi) >> 1;
            if (batch[mid] < target) lo = mid + 1; else hi = mid;
        }
        range[t] = lo;
    }
    __syncthreads();
    float cnt = (float)(range[1] - range[0]);
    if (t < 16) pld[t] = pooled[g * 16 + t] + cnt * b2[t];
    __syncthreads();
    if (t < 7) {
        float a = bl[t];
#pragma unroll
        for (int k = 0; k < 16; k++) a += pld[k] * Wl[k * 7 + t];
        logits[t] = a;
    }
    __syncthreads();
    if (t == 0) {
        float m = logits[0];
#pragma unroll
        for (int c = 1; c < 7; c++) m = fmaxf(m, logits[c]);
        float sum = 0.f;
#pragma unroll
        for (int c = 0; c < 7; c++) sum += expf(logits[c] - m);
        float lse = logf(sum) + m;
#pragma unroll
        for (int c = 0; c < 7; c++) out[g * 7 + c] = logits[c] - lse;
    }
}

extern "C" void kernel_launch(void* const* d_in, const int* in_sizes, int n_in,
                              void* d_out, int out_size, void* d_ws, size_t ws_size,
                              hipStream_t stream) {
    const float* x     = (const float*)d_in[0];
    const int*   ei    = (const int*)d_in[1];
    const int*   batch = (const int*)d_in[2];
    const float* W1    = (const float*)d_in[3];
    const float* b1    = (const float*)d_in[4];
    const float* W2    = (const float*)d_in[5];
    const float* b2    = (const float*)d_in[6];
    const float* Wl    = (const float*)d_in[7];
    const float* bl    = (const float*)d_in[8];
    float* out = (float*)d_out;

    const int* row = ei;            // sources
    const int* col = ei + N_EDGES;  // targets

    // ws layout (4-byte words). pairbuf becomes csr in place (k_finalize).
    int*    gcursor = (int*)d_ws;                      // @0        782 (pad 800)
    float*  pooled  = (float*)d_ws + 800;              // @800      16384 (1024*16)
    float*  dinv    = (float*)d_ws + 17200;            // @17200    100000
    int2*   rowse   = (int2*)((int*)d_ws + 117200);    // @117200   200000 words
    int*    pairbuf = (int*)d_ws + 317200;             // @317200   782*4608 = 3603456 (-> csr)
    __half* bufA16  = (__half*)((int*)d_ws + 3920656); // @3920656  200000 words (16B-aligned)
    __half* bufB16  = (__half*)((int*)d_ws + 4120656); // @4120656  800000 words (16B-aligned)

    const int BT = 256;

    hipMemsetAsync(gcursor, 0, 17184 * sizeof(int), stream);  // gcursor + pooled
    k_pair_scatter<<<NPS, BT, 0, stream>>>(row, col, gcursor, pairbuf);
    k_finalize<<<NBUCK, BT, 0, stream>>>(pairbuf, gcursor, rowse, dinv, x, bufA16);
    k_gather1<<<(N_NODES + 127) / 128, BT, 0, stream>>>((const uint2*)bufA16, pairbuf, rowse,
                                                        dinv, W1, b1, W2, bufB16);
    k_gather2<<<(N_NODES + 63) / 64, BT, 0, stream>>>((const uint2*)bufB16, pairbuf, rowse,
                                                      dinv, batch, pooled);
    k_head<<<N_GRAPHS, 64, 0, stream>>>(pooled, batch, b2, Wl, bl, out);
}